// Round 1
// baseline (765.899 us; speedup 1.0000x reference)
//
#include <hip/hip_runtime.h>

// GAT forward: h = x@W1; s_e = h[dst]·Wp[:64] + h[src]·Wp[64:] + bp;
// num = exp(leakyrelu(s)); denom = segsum(num, dst);
// alpha = num / (denom[src] + 1e-16); out = segsum(h[src]*alpha, dst) + bias.
// Factorization: a[n] = h[n]·Wp[:64], b[n] = h[n]·Wp[64:]; s_e = a[dst]+b[src]+bp.

#define NPW 4  // nodes per wave in node_transform

__global__ __launch_bounds__(256) void init_out_kernel(
    float* __restrict__ out, const float* __restrict__ bias, int total4)
{
    int idx = blockIdx.x * blockDim.x + threadIdx.x;
    if (idx >= total4) return;
    int c4 = idx & 15;  // 16 float4 per 64-wide row
    float4 b = reinterpret_cast<const float4*>(bias)[c4];
    reinterpret_cast<float4*>(out)[idx] = b;
}

__global__ __launch_bounds__(256) void node_transform_kernel(
    const float* __restrict__ x, const float* __restrict__ W1,
    const float* __restrict__ Wp,
    float* __restrict__ h, float* __restrict__ aArr, float* __restrict__ bArr,
    int N)
{
    __shared__ float sW1[128 * 64];          // 32 KB
    __shared__ float sX[4][NPW][128];        // 8 KB
    const int tid = threadIdx.x;
    const int w = tid >> 6, lane = tid & 63;

    // stage W1 (row-major 128x64), coalesced float4
    for (int i = tid * 4; i < 128 * 64; i += 256 * 4)
        *reinterpret_cast<float4*>(&sW1[i]) = *reinterpret_cast<const float4*>(&W1[i]);

    const float wpa = Wp[lane];        // dst-side (h_i) weight
    const float wpb = Wp[64 + lane];   // src-side (h_j) weight
    __syncthreads();

    const int stride = gridDim.x * (4 * NPW);
    for (int n0 = blockIdx.x * (4 * NPW); n0 < N; n0 += stride) {
        const int nb = n0 + w * NPW;
        #pragma unroll
        for (int m = 0; m < NPW; ++m) {
            int n = nb + m;
            if (n < N) {
                sX[w][m][lane]      = x[(size_t)n * 128 + lane];
                sX[w][m][lane + 64] = x[(size_t)n * 128 + 64 + lane];
            }
        }
        __syncthreads();

        float acc[NPW] = {0.f, 0.f, 0.f, 0.f};
        #pragma unroll
        for (int k4 = 0; k4 < 32; ++k4) {
            float4 xv[NPW];
            #pragma unroll
            for (int m = 0; m < NPW; ++m)
                xv[m] = *reinterpret_cast<const float4*>(&sX[w][m][k4 * 4]);
            #pragma unroll
            for (int kk = 0; kk < 4; ++kk) {
                float wv = sW1[(k4 * 4 + kk) * 64 + lane];
                #pragma unroll
                for (int m = 0; m < NPW; ++m)
                    acc[m] = fmaf(reinterpret_cast<const float*>(&xv[m])[kk], wv, acc[m]);
            }
        }

        #pragma unroll
        for (int m = 0; m < NPW; ++m) {
            int n = nb + m;
            if (n < N) {
                h[(size_t)n * 64 + lane] = acc[m];
                float a = acc[m] * wpa, b = acc[m] * wpb;
                #pragma unroll
                for (int off = 32; off; off >>= 1) {
                    a += __shfl_down(a, off);
                    b += __shfl_down(b, off);
                }
                if (lane == 0) { aArr[n] = a; bArr[n] = b; }
            }
        }
        __syncthreads();
    }
}

__global__ __launch_bounds__(256) void edge_score_kernel(
    const int* __restrict__ ei, const float* __restrict__ aArr,
    const float* __restrict__ bArr, const float* __restrict__ bp,
    float* __restrict__ numA, float* __restrict__ denom, int E)
{
    int e = blockIdx.x * blockDim.x + threadIdx.x;
    if (e >= E) return;
    int src = ei[e];
    int dst = ei[E + e];
    float s = aArr[dst] + bArr[src] + bp[0];
    s = (s >= 0.f) ? s : 0.2f * s;
    float nv = expf(s);
    numA[e] = nv;
    atomicAdd(&denom[dst], nv);
}

__global__ __launch_bounds__(256) void edge_aggregate_kernel(
    const int* __restrict__ ei, const float* __restrict__ h,
    const float* __restrict__ numA, const float* __restrict__ denom,
    float* __restrict__ out, int E)
{
    int gw = (blockIdx.x * blockDim.x + threadIdx.x) >> 6;  // one wave per edge
    int lane = threadIdx.x & 63;
    if (gw >= E) return;
    int src = ei[gw];
    int dst = ei[E + gw];
    float alpha = numA[gw] / (denom[src] + 1e-16f);  // NOTE: denom gathered at src, per reference
    float hj = h[(size_t)src * 64 + lane];
    atomicAdd(&out[(size_t)dst * 64 + lane], hj * alpha);
}

extern "C" void kernel_launch(void* const* d_in, const int* in_sizes, int n_in,
                              void* d_out, int out_size, void* d_ws, size_t ws_size,
                              hipStream_t stream) {
    const float* x    = (const float*)d_in[0];
    const int*   ei   = (const int*)d_in[1];
    // d_in[2] = rank_mapping (unused)
    const float* W1   = (const float*)d_in[3];
    const float* Wp   = (const float*)d_in[4];
    const float* bp   = (const float*)d_in[5];
    const float* bias = (const float*)d_in[6];
    float* out = (float*)d_out;

    const int N = in_sizes[0] / 128;
    const int E = in_sizes[1] / 2;

    // workspace layout (floats): h[N*64] | a[N] | b[N] | denom[N] | num[E]
    float* h     = (float*)d_ws;
    float* aArr  = h + (size_t)N * 64;
    float* bArr  = aArr + N;
    float* denom = bArr + N;
    float* numA  = denom + N;

    hipMemsetAsync(denom, 0, (size_t)N * sizeof(float), stream);

    int total4 = N * 16;
    init_out_kernel<<<(total4 + 255) / 256, 256, 0, stream>>>(out, bias, total4);

    node_transform_kernel<<<2048, 256, 0, stream>>>(x, W1, Wp, h, aArr, bArr, N);

    edge_score_kernel<<<(E + 255) / 256, 256, 0, stream>>>(ei, aArr, bArr, bp, numA, denom, E);

    edge_aggregate_kernel<<<(E + 3) / 4, 256, 0, stream>>>(ei, h, numA, denom, out, E);
}

// Round 2
// 415.147 us; speedup vs baseline: 1.8449x; 1.8449x over previous
//
#include <hip/hip_runtime.h>

// GAT forward: h = x@W1; s_e = h[dst]·Wp[:64] + h[src]·Wp[64:] + bp;
// num = exp(leakyrelu(s)); denom = segsum(num, dst);
// alpha = num / (denom[src] + 1e-16); out = segsum(h[src]*alpha, dst) + bias.
// Factorization: a[n] = h[n]·Wp[:64], b[n] = h[n]·Wp[64:]; s_e = a[dst]+b[src]+bp.

__global__ __launch_bounds__(256) void init_out_kernel(
    float* __restrict__ out, const float* __restrict__ bias, int total4)
{
    int idx = blockIdx.x * blockDim.x + threadIdx.x;
    if (idx >= total4) return;
    int c4 = idx & 15;  // 16 float4 per 64-wide row
    float4 b = reinterpret_cast<const float4*>(bias)[c4];
    reinterpret_cast<float4*>(out)[idx] = b;
}

// 6250 blocks x 16 nodes (N=100000 divides exactly). 4 waves/block, 4 nodes/wave.
// lane = output channel. W1 staged in LDS [k][o]; x rows staged in LDS and read
// as wave-uniform broadcasts. Single __syncthreads; no grid-stride loop.
__global__ __launch_bounds__(256) void node_transform_kernel(
    const float* __restrict__ x, const float* __restrict__ W1,
    const float* __restrict__ Wp,
    float* __restrict__ h, float* __restrict__ aArr, float* __restrict__ bArr,
    int N)
{
    __shared__ float sW1[128 * 64];   // 32 KB, [k][o]
    __shared__ float sX[4][4][128];   // 8 KB, [wave][node][k]
    const int tid = threadIdx.x;
    const int w = tid >> 6, lane = tid & 63;
    const int n0 = blockIdx.x * 16 + w * 4;

    // issue x loads early (8 floats/thread, coalesced 256B segments)
    float xr[8];
    #pragma unroll
    for (int m = 0; m < 4; ++m) {
        const float* xp = &x[(size_t)(n0 + m) * 128];
        xr[2 * m]     = xp[lane];
        xr[2 * m + 1] = xp[lane + 64];
    }

    // stage W1 (row-major 128x64), coalesced float4
    for (int i = tid * 4; i < 128 * 64; i += 256 * 4)
        *reinterpret_cast<float4*>(&sW1[i]) = *reinterpret_cast<const float4*>(&W1[i]);

    #pragma unroll
    for (int m = 0; m < 4; ++m) {
        sX[w][m][lane]      = xr[2 * m];
        sX[w][m][lane + 64] = xr[2 * m + 1];
    }

    const float wpa = Wp[lane];        // dst-side (h_i) weight
    const float wpb = Wp[64 + lane];   // src-side (h_j) weight
    __syncthreads();

    float acc0 = 0.f, acc1 = 0.f, acc2 = 0.f, acc3 = 0.f;
    const float* xr0 = sX[w][0];
    const float* xr1 = sX[w][1];
    const float* xr2 = sX[w][2];
    const float* xr3 = sX[w][3];
    #pragma unroll 4
    for (int k = 0; k < 128; ++k) {
        float wv = sW1[k * 64 + lane];   // 2-way bank alias: free
        acc0 = fmaf(xr0[k], wv, acc0);   // broadcast reads: free
        acc1 = fmaf(xr1[k], wv, acc1);
        acc2 = fmaf(xr2[k], wv, acc2);
        acc3 = fmaf(xr3[k], wv, acc3);
    }

    float accs[4] = {acc0, acc1, acc2, acc3};
    #pragma unroll
    for (int m = 0; m < 4; ++m) {
        const int n = n0 + m;
        h[(size_t)n * 64 + lane] = accs[m];
        float a = accs[m] * wpa, b = accs[m] * wpb;
        #pragma unroll
        for (int off = 32; off; off >>= 1) {
            a += __shfl_down(a, off);
            b += __shfl_down(b, off);
        }
        if (lane == 0) { aArr[n] = a; bArr[n] = b; }
    }
}

__global__ __launch_bounds__(256) void edge_score_kernel(
    const int* __restrict__ ei, const float* __restrict__ aArr,
    const float* __restrict__ bArr, const float* __restrict__ bp,
    float* __restrict__ numA, float* __restrict__ denom, int E)
{
    int e = blockIdx.x * blockDim.x + threadIdx.x;
    if (e >= E) return;
    int src = ei[e];
    int dst = ei[E + e];
    float s = aArr[dst] + bArr[src] + bp[0];
    s = (s >= 0.f) ? s : 0.2f * s;
    float nv = expf(s);
    numA[e] = nv;
    atomicAdd(&denom[dst], nv);
}

__global__ __launch_bounds__(256) void edge_aggregate_kernel(
    const int* __restrict__ ei, const float* __restrict__ h,
    const float* __restrict__ numA, const float* __restrict__ denom,
    float* __restrict__ out, int E)
{
    int gw = (blockIdx.x * blockDim.x + threadIdx.x) >> 6;  // one wave per edge
    int lane = threadIdx.x & 63;
    if (gw >= E) return;
    int src = ei[gw];
    int dst = ei[E + gw];
    float alpha = numA[gw] / (denom[src] + 1e-16f);  // denom gathered at src, per reference
    float hj = h[(size_t)src * 64 + lane];
    atomicAdd(&out[(size_t)dst * 64 + lane], hj * alpha);
}

extern "C" void kernel_launch(void* const* d_in, const int* in_sizes, int n_in,
                              void* d_out, int out_size, void* d_ws, size_t ws_size,
                              hipStream_t stream) {
    const float* x    = (const float*)d_in[0];
    const int*   ei   = (const int*)d_in[1];
    // d_in[2] = rank_mapping (unused)
    const float* W1   = (const float*)d_in[3];
    const float* Wp   = (const float*)d_in[4];
    const float* bp   = (const float*)d_in[5];
    const float* bias = (const float*)d_in[6];
    float* out = (float*)d_out;

    const int N = in_sizes[0] / 128;
    const int E = in_sizes[1] / 2;

    // workspace layout (floats): h[N*64] | a[N] | b[N] | denom[N] | num[E]
    float* h     = (float*)d_ws;
    float* aArr  = h + (size_t)N * 64;
    float* bArr  = aArr + N;
    float* denom = bArr + N;
    float* numA  = denom + N;

    hipMemsetAsync(denom, 0, (size_t)N * sizeof(float), stream);

    int total4 = N * 16;
    init_out_kernel<<<(total4 + 255) / 256, 256, 0, stream>>>(out, bias, total4);

    node_transform_kernel<<<(N + 15) / 16, 256, 0, stream>>>(x, W1, Wp, h, aArr, bArr, N);

    edge_score_kernel<<<(E + 255) / 256, 256, 0, stream>>>(ei, aArr, bArr, bp, numA, denom, E);

    edge_aggregate_kernel<<<(E + 3) / 4, 256, 0, stream>>>(ei, h, numA, denom, out, E);
}

// Round 3
// 331.888 us; speedup vs baseline: 2.3077x; 1.2509x over previous
//
#include <hip/hip_runtime.h>

// GAT forward, CSR-by-dst formulation:
//   h = x@W1; a[n]=h[n]·Wp[:64]; b[n]=h[n]·Wp[64:]
//   num_e = exp(leakyrelu(a[dst]+b[src]+bp))
//   denom[n] = sum_{e:dst=n} num_e           (segment sum via dst-sorted edges)
//   alpha_e = num_e / (denom[src_e]+1e-16)   (gathered at SRC, per reference quirk)
//   out[n]  = sum_{e:dst=n} h[src_e]*alpha_e + bias
// Edges counting-sorted by dst on device (hist -> scan -> scatter), so the
// aggregate is a per-node register reduction with one coalesced store: no
// atomics on out.

// ---------------- node transform: h = x@W1, a,b projections ----------------
// 6250 blocks x 16 nodes. 4 waves/block, 4 nodes/wave. lane = output channel.
__global__ __launch_bounds__(256) void node_transform_kernel(
    const float* __restrict__ x, const float* __restrict__ W1,
    const float* __restrict__ Wp,
    float* __restrict__ h, float* __restrict__ aArr, float* __restrict__ bArr,
    int N)
{
    __shared__ float sW1[128 * 64];   // 32 KB, [k][o]
    __shared__ float sX[4][4][128];   // 8 KB, [wave][node][k]
    const int tid = threadIdx.x;
    const int w = tid >> 6, lane = tid & 63;
    const int n0 = blockIdx.x * 16 + w * 4;

    float xr[8];
    #pragma unroll
    for (int m = 0; m < 4; ++m) {
        const float* xp = &x[(size_t)(n0 + m) * 128];
        xr[2 * m]     = xp[lane];
        xr[2 * m + 1] = xp[lane + 64];
    }

    for (int i = tid * 4; i < 128 * 64; i += 256 * 4)
        *reinterpret_cast<float4*>(&sW1[i]) = *reinterpret_cast<const float4*>(&W1[i]);

    #pragma unroll
    for (int m = 0; m < 4; ++m) {
        sX[w][m][lane]      = xr[2 * m];
        sX[w][m][lane + 64] = xr[2 * m + 1];
    }

    const float wpa = Wp[lane];
    const float wpb = Wp[64 + lane];
    __syncthreads();

    float acc0 = 0.f, acc1 = 0.f, acc2 = 0.f, acc3 = 0.f;
    const float* xr0 = sX[w][0];
    const float* xr1 = sX[w][1];
    const float* xr2 = sX[w][2];
    const float* xr3 = sX[w][3];
    #pragma unroll 4
    for (int k = 0; k < 128; ++k) {
        float wv = sW1[k * 64 + lane];   // 2-way bank alias: free
        acc0 = fmaf(xr0[k], wv, acc0);   // broadcast reads: free
        acc1 = fmaf(xr1[k], wv, acc1);
        acc2 = fmaf(xr2[k], wv, acc2);
        acc3 = fmaf(xr3[k], wv, acc3);
    }

    float accs[4] = {acc0, acc1, acc2, acc3};
    #pragma unroll
    for (int m = 0; m < 4; ++m) {
        const int n = n0 + m;
        h[(size_t)n * 64 + lane] = accs[m];
        float a = accs[m] * wpa, b = accs[m] * wpb;
        #pragma unroll
        for (int off = 32; off; off >>= 1) {
            a += __shfl_down(a, off);
            b += __shfl_down(b, off);
        }
        if (lane == 0) { aArr[n] = a; bArr[n] = b; }
    }
}

// ---------------- histogram of dst ----------------
__global__ __launch_bounds__(256) void hist_kernel(
    const int* __restrict__ ei, int* __restrict__ cnt, int E)
{
    int e = blockIdx.x * blockDim.x + threadIdx.x;
    if (e >= E) return;
    atomicAdd(&cnt[ei[E + e]], 1);
}

// ---------------- 3-kernel exclusive scan over cnt[N] ----------------
// block = 256 threads x 4 elements = 1024 per block
__global__ __launch_bounds__(256) void scan_reduce_kernel(
    const int* __restrict__ cnt, int* __restrict__ partial, int N)
{
    __shared__ int s[256];
    const int t = threadIdx.x;
    const int base = blockIdx.x * 1024 + t * 4;
    int sum = 0;
    #pragma unroll
    for (int j = 0; j < 4; ++j) {
        int n = base + j;
        sum += (n < N) ? cnt[n] : 0;
    }
    s[t] = sum;
    __syncthreads();
    for (int off = 128; off; off >>= 1) {
        if (t < off) s[t] += s[t + off];
        __syncthreads();
    }
    if (t == 0) partial[blockIdx.x] = s[0];
}

__global__ __launch_bounds__(128) void scan_partials_kernel(
    const int* __restrict__ partial, int* __restrict__ partialOff,
    int* __restrict__ offsets, int NB, int N, int E)
{
    __shared__ int s[128];
    const int t = threadIdx.x;
    int v = (t < NB) ? partial[t] : 0;
    s[t] = v;
    __syncthreads();
    for (int off = 1; off < 128; off <<= 1) {
        int u = (t >= off) ? s[t - off] : 0;
        __syncthreads();
        s[t] += u;
        __syncthreads();
    }
    if (t < NB) partialOff[t] = s[t] - v;   // exclusive
    if (t == 0) offsets[N] = E;
}

__global__ __launch_bounds__(256) void scan_final_kernel(
    const int* __restrict__ cnt, const int* __restrict__ partialOff,
    int* __restrict__ offsets, int* __restrict__ cursor, int N)
{
    __shared__ int s[256];
    const int t = threadIdx.x;
    const int base = blockIdx.x * 1024 + t * 4;
    int c[4];
    int sum = 0;
    #pragma unroll
    for (int j = 0; j < 4; ++j) {
        int n = base + j;
        c[j] = (n < N) ? cnt[n] : 0;
        sum += c[j];
    }
    s[t] = sum;
    __syncthreads();
    for (int off = 1; off < 256; off <<= 1) {
        int u = (t >= off) ? s[t - off] : 0;
        __syncthreads();
        s[t] += u;
        __syncthreads();
    }
    int run = partialOff[blockIdx.x] + s[t] - sum;  // exclusive base for this thread
    #pragma unroll
    for (int j = 0; j < 4; ++j) {
        int n = base + j;
        if (n < N) { offsets[n] = run; cursor[n] = run; }
        run += c[j];
    }
}

// ---------------- scatter edges into dst-sorted order ----------------
__global__ __launch_bounds__(256) void scatter_kernel(
    const int* __restrict__ ei, const float* __restrict__ aArr,
    const float* __restrict__ bArr, const float* __restrict__ bp,
    int* __restrict__ cursor,
    int* __restrict__ sortedSrc, float* __restrict__ sortedNum, int E)
{
    int e = blockIdx.x * blockDim.x + threadIdx.x;
    if (e >= E) return;
    int src = ei[e];
    int dst = ei[E + e];
    float s = aArr[dst] + bArr[src] + bp[0];
    s = (s >= 0.f) ? s : 0.2f * s;
    float num = __expf(s);
    int pos = atomicAdd(&cursor[dst], 1);
    sortedSrc[pos] = src;
    sortedNum[pos] = num;
}

// ---------------- denom[n] = segment sum of sortedNum ----------------
__global__ __launch_bounds__(256) void denom_kernel(
    const int* __restrict__ offsets, const float* __restrict__ sortedNum,
    float* __restrict__ denom, int N)
{
    int gw = (blockIdx.x * blockDim.x + threadIdx.x) >> 6;
    int lane = threadIdx.x & 63;
    if (gw >= N) return;
    int beg = offsets[gw], end = offsets[gw + 1];
    float s = 0.f;
    for (int e = beg + lane; e < end; e += 64) s += sortedNum[e];
    #pragma unroll
    for (int off = 32; off; off >>= 1) s += __shfl_down(s, off);
    if (lane == 0) denom[gw] = s;
}

// ---------------- aggregate: wave per dst node, lane = channel ----------------
__global__ __launch_bounds__(256) void aggregate_kernel(
    const int* __restrict__ offsets, const int* __restrict__ sortedSrc,
    const float* __restrict__ sortedNum, const float* __restrict__ denom,
    const float* __restrict__ h, const float* __restrict__ bias,
    float* __restrict__ out, int N)
{
    int gw = (blockIdx.x * blockDim.x + threadIdx.x) >> 6;
    int lane = threadIdx.x & 63;
    if (gw >= N) return;
    int beg = offsets[gw], end = offsets[gw + 1];
    float acc = 0.f;
    for (int e = beg; e < end; ++e) {
        int src = sortedSrc[e];                       // wave-uniform
        float alpha = sortedNum[e] / (denom[src] + 1e-16f);  // denom at SRC (ref quirk)
        acc = fmaf(h[(size_t)src * 64 + lane], alpha, acc);  // 256B coalesced gather
    }
    out[(size_t)gw * 64 + lane] = acc + bias[lane];
}

extern "C" void kernel_launch(void* const* d_in, const int* in_sizes, int n_in,
                              void* d_out, int out_size, void* d_ws, size_t ws_size,
                              hipStream_t stream) {
    const float* x    = (const float*)d_in[0];
    const int*   ei   = (const int*)d_in[1];
    // d_in[2] = rank_mapping (unused)
    const float* W1   = (const float*)d_in[3];
    const float* Wp   = (const float*)d_in[4];
    const float* bp   = (const float*)d_in[5];
    const float* bias = (const float*)d_in[6];
    float* out = (float*)d_out;

    const int N = in_sizes[0] / 128;
    const int E = in_sizes[1] / 2;
    const int NB = (N + 1023) / 1024;   // scan blocks (98 for N=100000, fits 128)

    // workspace layout (4B units):
    // h[N*64] | a[N] | b[N] | denom[N] | cnt[N] | offsets[N+1] | cursor[N] |
    // partial[128] | partialOff[128] | sortedSrc[E] | sortedNum[E]
    float* h          = (float*)d_ws;
    float* aArr       = h + (size_t)N * 64;
    float* bArr       = aArr + N;
    float* denom      = bArr + N;
    int*   cnt        = (int*)(denom + N);
    int*   offsets    = cnt + N;
    int*   cursor     = offsets + (N + 1);
    int*   partial    = cursor + N;
    int*   partialOff = partial + 128;
    int*   sortedSrc  = partialOff + 128;
    float* sortedNum  = (float*)(sortedSrc + E);

    hipMemsetAsync(cnt, 0, (size_t)N * sizeof(int), stream);

    node_transform_kernel<<<(N + 15) / 16, 256, 0, stream>>>(x, W1, Wp, h, aArr, bArr, N);

    hist_kernel<<<(E + 255) / 256, 256, 0, stream>>>(ei, cnt, E);

    scan_reduce_kernel<<<NB, 256, 0, stream>>>(cnt, partial, N);
    scan_partials_kernel<<<1, 128, 0, stream>>>(partial, partialOff, offsets, NB, N, E);
    scan_final_kernel<<<NB, 256, 0, stream>>>(cnt, partialOff, offsets, cursor, N);

    scatter_kernel<<<(E + 255) / 256, 256, 0, stream>>>(ei, aArr, bArr, bp, cursor,
                                                        sortedSrc, sortedNum, E);

    denom_kernel<<<(N * 64 + 255) / 256, 256, 0, stream>>>(offsets, sortedNum, denom, N);

    aggregate_kernel<<<(N * 64 + 255) / 256, 256, 0, stream>>>(offsets, sortedSrc, sortedNum,
                                                               denom, h, bias, out, N);
}

// Round 4
// 250.951 us; speedup vs baseline: 3.0520x; 1.3225x over previous
//
#include <hip/hip_runtime.h>

// GAT forward, CSR-by-dst formulation:
//   h = x@W1; a[n]=h[n]·Wp[:64]; b[n]=h[n]·Wp[64:]
//   num_e = exp(leakyrelu(a[dst]+b[src]+bp))
//   denom[n] = sum_{e:dst=n} num_e
//   hh[n]   = h[n] / (denom[n]+1e-16)        (bf16, in-place over h rows)
//   out[n]  = sum_{e:dst=n} num_e * hh[src_e] + bias   (denom at SRC = ref quirk)
// Edges counting-sorted by dst on device (hist -> scan -> scatter): aggregate is
// a per-node register reduction, no atomics on out.

static __device__ __forceinline__ float bf2f(unsigned short u) {
    unsigned v = (unsigned)u << 16;
    return __builtin_bit_cast(float, v);
}
static __device__ __forceinline__ unsigned short f2bf(float f) {
    unsigned u = __builtin_bit_cast(unsigned, f);
    u = (u + 0x7FFFu + ((u >> 16) & 1u)) >> 16;   // round-to-nearest-even
    return (unsigned short)u;
}

// ---------------- node transform: h = x@W1, a,b projections ----------------
// 6250 blocks x 16 nodes. 4 waves/block, 4 nodes/wave, lane = output channel.
// W1 transposed in LDS [o][k] pad 132 (ds_read_b128, uniform bank load);
// x rows read via wave-uniform (readfirstlane) addresses -> scalar/broadcast path.
__global__ __launch_bounds__(256) void node_transform_kernel(
    const float* __restrict__ x, const float* __restrict__ W1,
    const float* __restrict__ Wp,
    float* __restrict__ h, float* __restrict__ aArr, float* __restrict__ bArr,
    int N)
{
    __shared__ float sW1t[64 * 132];   // [o][k], 33 KB
    const int tid = threadIdx.x;
    const int w = tid >> 6, lane = tid & 63;

    // stage transposed: flat i: k=i>>6, o=i&63 -> sW1t[o*132+k]
    for (int i = tid; i < 128 * 64; i += 256)
        sW1t[(i & 63) * 132 + (i >> 6)] = W1[i];

    const float wpa = Wp[lane];
    const float wpb = Wp[64 + lane];
    __syncthreads();

    const int n0 = __builtin_amdgcn_readfirstlane(blockIdx.x * 16 + w * 4);
    const float* xp0 = x + (size_t)n0 * 128;

    float acc[4] = {0.f, 0.f, 0.f, 0.f};
    #pragma unroll 4
    for (int k4 = 0; k4 < 32; ++k4) {
        float4 wv = *reinterpret_cast<const float4*>(&sW1t[lane * 132 + k4 * 4]);
        #pragma unroll
        for (int m = 0; m < 4; ++m) {
            float4 xv = *reinterpret_cast<const float4*>(xp0 + m * 128 + k4 * 4);
            acc[m] = fmaf(xv.x, wv.x, acc[m]);
            acc[m] = fmaf(xv.y, wv.y, acc[m]);
            acc[m] = fmaf(xv.z, wv.z, acc[m]);
            acc[m] = fmaf(xv.w, wv.w, acc[m]);
        }
    }

    #pragma unroll
    for (int m = 0; m < 4; ++m) {
        const int n = n0 + m;
        h[(size_t)n * 64 + lane] = acc[m];
        float a = acc[m] * wpa, b = acc[m] * wpb;
        #pragma unroll
        for (int off = 32; off; off >>= 1) {
            a += __shfl_down(a, off);
            b += __shfl_down(b, off);
        }
        if (lane == 0) { aArr[n] = a; bArr[n] = b; }
    }
}

// ---------------- histogram of dst ----------------
__global__ __launch_bounds__(256) void hist_kernel(
    const int* __restrict__ ei, int* __restrict__ cnt, int E)
{
    int e = blockIdx.x * blockDim.x + threadIdx.x;
    if (e >= E) return;
    atomicAdd(&cnt[ei[E + e]], 1);
}

// ---------------- 3-kernel exclusive scan over cnt[N] ----------------
__global__ __launch_bounds__(256) void scan_reduce_kernel(
    const int* __restrict__ cnt, int* __restrict__ partial, int N)
{
    __shared__ int s[256];
    const int t = threadIdx.x;
    const int base = blockIdx.x * 1024 + t * 4;
    int sum = 0;
    #pragma unroll
    for (int j = 0; j < 4; ++j) {
        int n = base + j;
        sum += (n < N) ? cnt[n] : 0;
    }
    s[t] = sum;
    __syncthreads();
    for (int off = 128; off; off >>= 1) {
        if (t < off) s[t] += s[t + off];
        __syncthreads();
    }
    if (t == 0) partial[blockIdx.x] = s[0];
}

__global__ __launch_bounds__(128) void scan_partials_kernel(
    const int* __restrict__ partial, int* __restrict__ partialOff,
    int* __restrict__ offsets, int NB, int N, int E)
{
    __shared__ int s[128];
    const int t = threadIdx.x;
    int v = (t < NB) ? partial[t] : 0;
    s[t] = v;
    __syncthreads();
    for (int off = 1; off < 128; off <<= 1) {
        int u = (t >= off) ? s[t - off] : 0;
        __syncthreads();
        s[t] += u;
        __syncthreads();
    }
    if (t < NB) partialOff[t] = s[t] - v;   // exclusive
    if (t == 0) offsets[N] = E;
}

__global__ __launch_bounds__(256) void scan_final_kernel(
    const int* __restrict__ cnt, const int* __restrict__ partialOff,
    int* __restrict__ offsets, int* __restrict__ cursor, int N)
{
    __shared__ int s[256];
    const int t = threadIdx.x;
    const int base = blockIdx.x * 1024 + t * 4;
    int c[4];
    int sum = 0;
    #pragma unroll
    for (int j = 0; j < 4; ++j) {
        int n = base + j;
        c[j] = (n < N) ? cnt[n] : 0;
        sum += c[j];
    }
    s[t] = sum;
    __syncthreads();
    for (int off = 1; off < 256; off <<= 1) {
        int u = (t >= off) ? s[t - off] : 0;
        __syncthreads();
        s[t] += u;
        __syncthreads();
    }
    int run = partialOff[blockIdx.x] + s[t] - sum;
    #pragma unroll
    for (int j = 0; j < 4; ++j) {
        int n = base + j;
        if (n < N) { offsets[n] = run; cursor[n] = run; }
        run += c[j];
    }
}

// ---------------- scatter edges into dst-sorted order ----------------
__global__ __launch_bounds__(256) void scatter_kernel(
    const int* __restrict__ ei, const float* __restrict__ aArr,
    const float* __restrict__ bArr, const float* __restrict__ bp,
    int* __restrict__ cursor,
    int* __restrict__ sortedSrc, float* __restrict__ sortedNum, int E)
{
    int e = blockIdx.x * blockDim.x + threadIdx.x;
    if (e >= E) return;
    int src = ei[e];
    int dst = ei[E + e];
    float s = aArr[dst] + bArr[src] + bp[0];
    s = (s >= 0.f) ? s : 0.2f * s;
    float num = __expf(s);
    int pos = atomicAdd(&cursor[dst], 1);
    sortedSrc[pos] = src;
    sortedNum[pos] = num;
}

// ---------------- denom + hh: wave per node ----------------
// denom = segment sum of sortedNum; hh = h/denom as bf16 written in-place into
// the FIRST HALF of this node's fp32 h row (row-exclusive per wave -> safe).
__global__ __launch_bounds__(256) void denom_hh_kernel(
    const int* __restrict__ offsets, const float* __restrict__ sortedNum,
    float* __restrict__ h, int N)
{
    int gw = (blockIdx.x * blockDim.x + threadIdx.x) >> 6;
    int lane = threadIdx.x & 63;
    if (gw >= N) return;
    int beg = offsets[gw], end = offsets[gw + 1];
    float s = 0.f;
    for (int e = beg + lane; e < end; e += 64) s += sortedNum[e];
    #pragma unroll
    for (int off = 32; off; off >>= 1) s += __shfl_down(s, off);
    s = __shfl(s, 0);
    float inv = 1.f / (s + 1e-16f);
    float hv = h[(size_t)gw * 64 + lane];
    asm volatile("" ::: "memory");   // order read-before-aliased-write
    unsigned short* row = reinterpret_cast<unsigned short*>(h) + (size_t)gw * 128;
    row[lane] = f2bf(hv * inv);
}

// ---------------- aggregate: wave per dst node, lane = channel ----------------
// Coalesced preload of up to 64 (src,num) pairs, shfl-broadcast, 4 gathers in flight.
__global__ __launch_bounds__(256) void aggregate_kernel(
    const int* __restrict__ offsets, const int* __restrict__ sortedSrc,
    const float* __restrict__ sortedNum, const unsigned short* __restrict__ hhB,
    const float* __restrict__ bias, float* __restrict__ out, int N)
{
    int gw = (blockIdx.x * blockDim.x + threadIdx.x) >> 6;
    int lane = threadIdx.x & 63;
    if (gw >= N) return;
    int beg = offsets[gw], end = offsets[gw + 1];
    float acc = 0.f;
    for (int e0 = beg; e0 < end; e0 += 64) {
        int idx = e0 + lane;
        int srcL = 0; float numL = 0.f;
        if (idx < end) { srcL = sortedSrc[idx]; numL = sortedNum[idx]; }
        int cnt = min(64, end - e0);
        int j = 0;
        for (; j + 4 <= cnt; j += 4) {
            int s0 = __shfl(srcL, j),     s1 = __shfl(srcL, j + 1);
            int s2 = __shfl(srcL, j + 2), s3 = __shfl(srcL, j + 3);
            float w0 = __shfl(numL, j),     w1 = __shfl(numL, j + 1);
            float w2 = __shfl(numL, j + 2), w3 = __shfl(numL, j + 3);
            unsigned short g0 = hhB[(size_t)s0 * 128 + lane];
            unsigned short g1 = hhB[(size_t)s1 * 128 + lane];
            unsigned short g2 = hhB[(size_t)s2 * 128 + lane];
            unsigned short g3 = hhB[(size_t)s3 * 128 + lane];
            acc = fmaf(bf2f(g0), w0, acc);
            acc = fmaf(bf2f(g1), w1, acc);
            acc = fmaf(bf2f(g2), w2, acc);
            acc = fmaf(bf2f(g3), w3, acc);
        }
        for (; j < cnt; ++j) {
            int sj = __shfl(srcL, j);
            float wj = __shfl(numL, j);
            acc = fmaf(bf2f(hhB[(size_t)sj * 128 + lane]), wj, acc);
        }
    }
    out[(size_t)gw * 64 + lane] = acc + bias[lane];
}

extern "C" void kernel_launch(void* const* d_in, const int* in_sizes, int n_in,
                              void* d_out, int out_size, void* d_ws, size_t ws_size,
                              hipStream_t stream) {
    const float* x    = (const float*)d_in[0];
    const int*   ei   = (const int*)d_in[1];
    // d_in[2] = rank_mapping (unused)
    const float* W1   = (const float*)d_in[3];
    const float* Wp   = (const float*)d_in[4];
    const float* bp   = (const float*)d_in[5];
    const float* bias = (const float*)d_in[6];
    float* out = (float*)d_out;

    const int N = in_sizes[0] / 128;
    const int E = in_sizes[1] / 2;
    const int NB = (N + 1023) / 1024;   // 98 for N=100000

    // workspace (4B units):
    // h[N*64] | a[N] | b[N] | cnt[N] | offsets[N+1] | cursor[N] |
    // partial[128] | partialOff[128] | sortedSrc[E] | sortedNum[E]
    float* h          = (float*)d_ws;
    float* aArr       = h + (size_t)N * 64;
    float* bArr       = aArr + N;
    int*   cnt        = (int*)(bArr + N);
    int*   offsets    = cnt + N;
    int*   cursor     = offsets + (N + 1);
    int*   partial    = cursor + N;
    int*   partialOff = partial + 128;
    int*   sortedSrc  = partialOff + 128;
    float* sortedNum  = (float*)(sortedSrc + E);

    hipMemsetAsync(cnt, 0, (size_t)N * sizeof(int), stream);

    node_transform_kernel<<<(N + 15) / 16, 256, 0, stream>>>(x, W1, Wp, h, aArr, bArr, N);

    hist_kernel<<<(E + 255) / 256, 256, 0, stream>>>(ei, cnt, E);

    scan_reduce_kernel<<<NB, 256, 0, stream>>>(cnt, partial, N);
    scan_partials_kernel<<<1, 128, 0, stream>>>(partial, partialOff, offsets, NB, N, E);
    scan_final_kernel<<<NB, 256, 0, stream>>>(cnt, partialOff, offsets, cursor, N);

    scatter_kernel<<<(E + 255) / 256, 256, 0, stream>>>(ei, aArr, bArr, bp, cursor,
                                                        sortedSrc, sortedNum, E);

    denom_hh_kernel<<<(N * 64 + 255) / 256, 256, 0, stream>>>(offsets, sortedNum, h, N);

    aggregate_kernel<<<(N * 64 + 255) / 256, 256, 0, stream>>>(
        offsets, sortedSrc, sortedNum,
        reinterpret_cast<const unsigned short*>(h), bias, out, N);
}

// Round 6
// 249.151 us; speedup vs baseline: 3.0740x; 1.0072x over previous
//
#include <hip/hip_runtime.h>

// GAT forward, CSR-by-dst formulation:
//   h = x@W1; a[n]=h[n]·Wp[:64]; b[n]=h[n]·Wp[64:]
//   num_e = exp(leakyrelu(a[dst]+b[src]+bp))
//   denom[n] = sum_{e:dst=n} num_e
//   hh[n]   = h[n] / (denom[n]+1e-16)        (bf16, in-place over h rows)
//   out[n]  = sum_{e:dst=n} num_e * hh[src_e] + bias   (denom at SRC = ref quirk)
// Edges counting-sorted by dst (hist -> scan -> scatter of int2{src,num}):
// aggregate is a per-node register reduction, no atomics on out.

static __device__ __forceinline__ float bf2f(unsigned short u) {
    unsigned v = (unsigned)u << 16;
    return __builtin_bit_cast(float, v);
}
static __device__ __forceinline__ unsigned short f2bf(float f) {
    unsigned u = __builtin_bit_cast(unsigned, f);
    u = (u + 0x7FFFu + ((u >> 16) & 1u)) >> 16;   // round-to-nearest-even
    return (unsigned short)u;
}

// ---------------- node transform: h = x@W1, a,b projections ----------------
// 6250 blocks x 16 nodes. 4 waves/block, 4 nodes/wave, lane = output channel.
__global__ __launch_bounds__(256) void node_transform_kernel(
    const float* __restrict__ x, const float* __restrict__ W1,
    const float* __restrict__ Wp,
    float* __restrict__ h, float* __restrict__ aArr, float* __restrict__ bArr,
    int N)
{
    __shared__ float sW1t[64 * 132];   // [o][k], 33 KB
    const int tid = threadIdx.x;
    const int w = tid >> 6, lane = tid & 63;

    // stage transposed: flat i: k=i>>6, o=i&63 -> sW1t[o*132+k]
    for (int i = tid; i < 128 * 64; i += 256)
        sW1t[(i & 63) * 132 + (i >> 6)] = W1[i];

    const float wpa = Wp[lane];
    const float wpb = Wp[64 + lane];
    __syncthreads();

    const int n0 = __builtin_amdgcn_readfirstlane(blockIdx.x * 16 + w * 4);
    const float* xp0 = x + (size_t)n0 * 128;

    float acc[4] = {0.f, 0.f, 0.f, 0.f};
    #pragma unroll 4
    for (int k4 = 0; k4 < 32; ++k4) {
        float4 wv = *reinterpret_cast<const float4*>(&sW1t[lane * 132 + k4 * 4]);
        #pragma unroll
        for (int m = 0; m < 4; ++m) {
            float4 xv = *reinterpret_cast<const float4*>(xp0 + m * 128 + k4 * 4);
            acc[m] = fmaf(xv.x, wv.x, acc[m]);
            acc[m] = fmaf(xv.y, wv.y, acc[m]);
            acc[m] = fmaf(xv.z, wv.z, acc[m]);
            acc[m] = fmaf(xv.w, wv.w, acc[m]);
        }
    }

    #pragma unroll
    for (int m = 0; m < 4; ++m) {
        const int n = n0 + m;
        h[(size_t)n * 64 + lane] = acc[m];
        float a = acc[m] * wpa, b = acc[m] * wpb;
        #pragma unroll
        for (int off = 32; off; off >>= 1) {
            a += __shfl_down(a, off);
            b += __shfl_down(b, off);
        }
        if (lane == 0) { aArr[n] = a; bArr[n] = b; }
    }
}

// ---------------- histogram of dst ----------------
__global__ __launch_bounds__(256) void hist_kernel(
    const int* __restrict__ ei, int* __restrict__ cnt, int E)
{
    int e = blockIdx.x * blockDim.x + threadIdx.x;
    if (e >= E) return;
    atomicAdd(&cnt[ei[E + e]], 1);
}

// ---------------- 3-kernel exclusive scan over cnt[N] ----------------
__global__ __launch_bounds__(256) void scan_reduce_kernel(
    const int* __restrict__ cnt, int* __restrict__ partial, int N)
{
    __shared__ int s[256];
    const int t = threadIdx.x;
    const int base = blockIdx.x * 1024 + t * 4;
    int sum = 0;
    #pragma unroll
    for (int j = 0; j < 4; ++j) {
        int n = base + j;
        sum += (n < N) ? cnt[n] : 0;
    }
    s[t] = sum;
    __syncthreads();
    for (int off = 128; off; off >>= 1) {
        if (t < off) s[t] += s[t + off];
        __syncthreads();
    }
    if (t == 0) partial[blockIdx.x] = s[0];
}

__global__ __launch_bounds__(128) void scan_partials_kernel(
    const int* __restrict__ partial, int* __restrict__ partialOff,
    int* __restrict__ offsets, int NB, int N, int E)
{
    __shared__ int s[128];
    const int t = threadIdx.x;
    int v = (t < NB) ? partial[t] : 0;
    s[t] = v;
    __syncthreads();
    for (int off = 1; off < 128; off <<= 1) {
        int u = (t >= off) ? s[t - off] : 0;
        __syncthreads();
        s[t] += u;
        __syncthreads();
    }
    if (t < NB) partialOff[t] = s[t] - v;   // exclusive
    if (t == 0) offsets[N] = E;
}

__global__ __launch_bounds__(256) void scan_final_kernel(
    const int* __restrict__ cnt, const int* __restrict__ partialOff,
    int* __restrict__ offsets, int* __restrict__ cursor, int N)
{
    __shared__ int s[256];
    const int t = threadIdx.x;
    const int base = blockIdx.x * 1024 + t * 4;
    int c[4];
    int sum = 0;
    #pragma unroll
    for (int j = 0; j < 4; ++j) {
        int n = base + j;
        c[j] = (n < N) ? cnt[n] : 0;
        sum += c[j];
    }
    s[t] = sum;
    __syncthreads();
    for (int off = 1; off < 256; off <<= 1) {
        int u = (t >= off) ? s[t - off] : 0;
        __syncthreads();
        s[t] += u;
        __syncthreads();
    }
    int run = partialOff[blockIdx.x] + s[t] - sum;
    #pragma unroll
    for (int j = 0; j < 4; ++j) {
        int n = base + j;
        if (n < N) { offsets[n] = run; cursor[n] = run; }
        run += c[j];
    }
}

// ---------------- scatter edges into dst-sorted order (one int2 store) ------
__global__ __launch_bounds__(256) void scatter_kernel(
    const int* __restrict__ ei, const float* __restrict__ aArr,
    const float* __restrict__ bArr, const float* __restrict__ bp,
    int* __restrict__ cursor, int2* __restrict__ sortedPair, int E)
{
    int e = blockIdx.x * blockDim.x + threadIdx.x;
    if (e >= E) return;
    int src = ei[e];
    int dst = ei[E + e];
    float s = aArr[dst] + bArr[src] + bp[0];
    s = (s >= 0.f) ? s : 0.2f * s;
    float num = __expf(s);
    int pos = atomicAdd(&cursor[dst], 1);
    sortedPair[pos] = make_int2(src, __float_as_int(num));
}

// ---------------- denom + hh: wave per node ----------------
// denom = segment sum of num; hh = h/denom as bf16 written in-place into the
// FIRST HALF of this node's fp32 h row (row-exclusive per wave -> safe).
__global__ __launch_bounds__(256) void denom_hh_kernel(
    const int* __restrict__ offsets, const int2* __restrict__ sortedPair,
    float* __restrict__ h, int N)
{
    int gw = (blockIdx.x * blockDim.x + threadIdx.x) >> 6;
    int lane = threadIdx.x & 63;
    if (gw >= N) return;
    int beg = offsets[gw], end = offsets[gw + 1];
    float s = 0.f;
    for (int e = beg + lane; e < end; e += 64) s += __int_as_float(sortedPair[e].y);
    #pragma unroll
    for (int off = 32; off; off >>= 1) s += __shfl_down(s, off);
    s = __shfl(s, 0);
    float inv = 1.f / (s + 1e-16f);
    float hv = h[(size_t)gw * 64 + lane];
    asm volatile("" ::: "memory");   // order read-before-aliased-write
    unsigned short* row = reinterpret_cast<unsigned short*>(h) + (size_t)gw * 128;
    row[lane] = f2bf(hv * inv);
}

// ---------------- aggregate: wave per dst node, 2 edges per gather ----------
// hh row = 64 bf16 packed in the first 32 dwords of a 64-dword fp32 row:
// row base for node s is s*64 dwords (NOT s*32 — that was round 5's NaN bug).
// half = lane>>5 picks edge j / j+1; lane&31 picks a bf16x2 channel pair.
// One dword gather serves 2 channels; the wave covers 2 edges per instruction.
// shfl_xor(32) merges the two half-wave partials.
__global__ __launch_bounds__(256) void aggregate_kernel(
    const int* __restrict__ offsets, const int2* __restrict__ sortedPair,
    const unsigned* __restrict__ hhW, const float* __restrict__ bias,
    float* __restrict__ out, int N)
{
    int gw = (blockIdx.x * blockDim.x + threadIdx.x) >> 6;
    int lane = threadIdx.x & 63;
    if (gw >= N) return;
    int beg = offsets[gw], end = offsets[gw + 1];
    const int half = lane >> 5;      // which edge of the pair-step
    const int cp = lane & 31;        // channel pair index
    float accx = 0.f, accy = 0.f;
    for (int e0 = beg; e0 < end; e0 += 64) {
        int idx = e0 + lane;
        int2 p = (idx < end) ? sortedPair[idx] : make_int2(0, 0);
        int cnt = min(64, end - e0);
        int j = 0;
        for (; j + 8 <= cnt; j += 8) {
            #pragma unroll
            for (int u = 0; u < 4; ++u) {
                int jj = j + 2 * u + half;
                int s = __shfl(p.x, jj);
                float wv = __shfl(__int_as_float(p.y), jj);
                unsigned g = hhW[(size_t)s * 64 + cp];
                accx = fmaf(bf2f((unsigned short)(g & 0xFFFFu)), wv, accx);
                accy = fmaf(bf2f((unsigned short)(g >> 16)), wv, accy);
            }
        }
        for (; j < cnt; j += 2) {
            int jj = j + half;
            bool v = jj < cnt;
            int s = __shfl(p.x, v ? jj : j);
            float wv = v ? __shfl(__int_as_float(p.y), jj) : 0.f;
            unsigned g = hhW[(size_t)s * 64 + cp];
            accx = fmaf(bf2f((unsigned short)(g & 0xFFFFu)), wv, accx);
            accy = fmaf(bf2f((unsigned short)(g >> 16)), wv, accy);
        }
    }
    accx += __shfl_xor(accx, 32);
    accy += __shfl_xor(accy, 32);
    if (lane < 32) {
        float2 b = reinterpret_cast<const float2*>(bias)[cp];
        float2 o; o.x = accx + b.x; o.y = accy + b.y;
        reinterpret_cast<float2*>(out)[(size_t)gw * 32 + cp] = o;
    }
}

extern "C" void kernel_launch(void* const* d_in, const int* in_sizes, int n_in,
                              void* d_out, int out_size, void* d_ws, size_t ws_size,
                              hipStream_t stream) {
    const float* x    = (const float*)d_in[0];
    const int*   ei   = (const int*)d_in[1];
    // d_in[2] = rank_mapping (unused)
    const float* W1   = (const float*)d_in[3];
    const float* Wp   = (const float*)d_in[4];
    const float* bp   = (const float*)d_in[5];
    const float* bias = (const float*)d_in[6];
    float* out = (float*)d_out;

    const int N = in_sizes[0] / 128;
    const int E = in_sizes[1] / 2;
    const int NB = (N + 1023) / 1024;   // 98 for N=100000

    // workspace (4B units):
    // h[N*64] | a[N] | b[N] | cnt[N] | offsets[N+1] | cursor[N] |
    // partial[128] | partialOff[128] | sortedPair[E] (int2)
    float* h          = (float*)d_ws;
    float* aArr       = h + (size_t)N * 64;
    float* bArr       = aArr + N;
    int*   cnt        = (int*)(bArr + N);
    int*   offsets    = cnt + N;
    int*   cursor     = offsets + (N + 1);
    int*   partial    = cursor + N;
    int*   partialOff = partial + 128;
    int2*  sortedPair = (int2*)(partialOff + 128);

    hipMemsetAsync(cnt, 0, (size_t)N * sizeof(int), stream);

    node_transform_kernel<<<(N + 15) / 16, 256, 0, stream>>>(x, W1, Wp, h, aArr, bArr, N);

    hist_kernel<<<(E + 255) / 256, 256, 0, stream>>>(ei, cnt, E);

    scan_reduce_kernel<<<NB, 256, 0, stream>>>(cnt, partial, N);
    scan_partials_kernel<<<1, 128, 0, stream>>>(partial, partialOff, offsets, NB, N, E);
    scan_final_kernel<<<NB, 256, 0, stream>>>(cnt, partialOff, offsets, cursor, N);

    scatter_kernel<<<(E + 255) / 256, 256, 0, stream>>>(ei, aArr, bArr, bp, cursor,
                                                        sortedPair, E);

    denom_hh_kernel<<<(N * 64 + 255) / 256, 256, 0, stream>>>(offsets, sortedPair, h, N);

    aggregate_kernel<<<(N * 64 + 255) / 256, 256, 0, stream>>>(
        offsets, sortedPair, reinterpret_cast<const unsigned*>(h), bias, out, N);
}